// Round 4
// baseline (247.288 us; speedup 1.0000x reference)
//
#include <hip/hip_runtime.h>

#define N_CELLTYPE 50
#define M_PER_CT   2000
#define N_FEATURE  20000
#define N_CELL     512
#define R_TOTAL    (N_CELLTYPE * M_PER_CT)   // 100000 rows of z
#define TR         32                        // rows per tile  (100000/32 = 3125 exact)
#define TC         512                       // full x row per block
#define NTHREADS   512

typedef float vfloat4 __attribute__((ext_vector_type(4)));

// Gather + scale + transpose, one full x-row per tile-row.
//   read : x[idx[r]][0..511]    -> each wave-instr reads 1KB contiguous
//   write: out[c*100000 + r0+4q..+3] -> 128B-aligned full-line segments, NT
// LDS swizzle (no pad): row r keeps float4 q at column (q + (r>>2)) & 127.
//   -> load phase stays ds_write_b128-aligned; store-phase b32 reads land
//      2-way per bank (free, m136) instead of 4-way with the +4 pad.
__global__ __launch_bounds__(NTHREADS) void ct_scale_transpose(
    const float* __restrict__ x, const float* __restrict__ w,
    const int* __restrict__ idx, float* __restrict__ out) {
  __shared__ float tile[TR][TC];   // 64 KB -> 2 blocks/CU
  __shared__ int   srow[TR];
  __shared__ float sw[TR];

  const int r0 = blockIdx.x * TR;
  const int t  = threadIdx.x;

  if (t < TR) {
    const int r = r0 + t;
    srow[t] = idx[r];
    sw[t]   = w[r / M_PER_CT];
  }
  __syncthreads();

  // ---- Load phase: 32 rows x 128 float4 = 4096, 8 per thread. ----
  // Stage all 8 loads in registers first -> 8 outstanding global loads.
  float4 vv[8];
#pragma unroll
  for (int i = 0; i < 8; ++i) {
    const int linear = i * NTHREADS + t;
    const int row = linear >> 7;    // 0..31 (wave-uniform)
    const int q   = linear & 127;   // float4 index within row
    vv[i] = *reinterpret_cast<const float4*>(
        x + (long)srow[row] * N_CELL + q * 4);
  }
#pragma unroll
  for (int i = 0; i < 8; ++i) {
    const int linear = i * NTHREADS + t;
    const int row = linear >> 7;
    const int q   = linear & 127;
    const float s = sw[row];
    vfloat4 sv;
    sv.x = vv[i].x * s; sv.y = vv[i].y * s;
    sv.z = vv[i].z * s; sv.w = vv[i].w * s;
    const int p4 = (q + (row >> 2)) & 127;          // swizzle
    *reinterpret_cast<vfloat4*>(&tile[row][p4 * 4]) = sv;
  }
  __syncthreads();

  // ---- Store phase: 512 c x 8 r-chunks = 4096 float4, 8 per thread. ----
#pragma unroll
  for (int i = 0; i < 8; ++i) {
    const int linear = i * NTHREADS + t;
    const int c  = linear >> 3;     // 0..511
    const int q  = linear & 7;      // r-chunk: rows 4q..4q+3 (row>>2 == q)
    const int p4 = ((c >> 2) + q) & 127;            // swizzled column
    const int e  = p4 * 4 + (c & 3);
    vfloat4 v;
    v.x = tile[4 * q + 0][e];
    v.y = tile[4 * q + 1][e];
    v.z = tile[4 * q + 2][e];
    v.w = tile[4 * q + 3][e];
    __builtin_nontemporal_store(
        v, reinterpret_cast<vfloat4*>(out + (long)c * R_TOTAL + r0 + 4 * q));
  }
}

extern "C" void kernel_launch(void* const* d_in, const int* in_sizes, int n_in,
                              void* d_out, int out_size, void* d_ws, size_t ws_size,
                              hipStream_t stream) {
  const float* x   = (const float*)d_in[0];
  const float* w   = (const float*)d_in[1];
  const int*   idx = (const int*)d_in[2];
  float*       out = (float*)d_out;

  ct_scale_transpose<<<dim3(R_TOTAL / TR), NTHREADS, 0, stream>>>(x, w, idx, out);
}